// Round 1
// 166.265 us; speedup vs baseline: 1.0410x; 1.0410x over previous
//
#include <hip/hip_runtime.h>
#include <math.h>

#define N_OBJ 1024
#define C_DET 8
#define C_SEG 4
#define HW    784      // 28*28
#define HW4   196      // HW/4 (float4 units)
#define NBLK  128      // best-measured grid: (128, 8)
#define NPART (C_DET * 5 * NBLK)   // 5120 partial floats

typedef float f32x4 __attribute__((ext_vector_type(4)));

// d_ws layout: float partial[NPART], as 40 contiguous rows of NBLK:
// partial[(c*5 + k)*NBLK + bx]: k=0 denom partial, k=1+i -> A[c][i] partial.

__global__ __launch_bounds__(256) void overlap_kernel(
    const float* __restrict__ det,   // [N_OBJ, C_DET, HW]
    const float* __restrict__ seg,   // [N_OBJ, C_DET, C_SEG, HW]
    const int* __restrict__ edge_i,
    const int* __restrict__ edge_j,
    const int n_edges,
    float* __restrict__ partial)
{
    const int c   = blockIdx.y;
    const int bx  = blockIdx.x;
    const int tid = threadIdx.x;

    // Only A[c][i] for edges (i, c) is ever read by finalize -> build a
    // plane mask for this det class and skip the dead seg planes' loads.
    // Edge list is tiny (16 entries) and wave-uniform; readfirstlane forces
    // the mask into an SGPR so the plane branches are scalar (s_cbranch).
    int mask = 0;
    for (int e = 0; e < n_edges; ++e)
        if (edge_j[e] == c) mask |= 1 << edge_i[e];
    mask = __builtin_amdgcn_readfirstlane(mask);

    float accD = 0.f, a0 = 0.f, a1 = 0.f, a2 = 0.f, a3 = 0.f;

    const int total4 = N_OBJ * HW4;  // 200704
    const int step   = NBLK * 256;   // 32768

    auto body = [&](int t4) {
        const int n  = t4 / HW4;                 // magic-mul div
        const int p4 = t4 - n * HW4;
        const int drow = (n * C_DET + c) * HW + p4 * 4;
        const f32x4 d = __builtin_nontemporal_load(
            reinterpret_cast<const f32x4*>(det + drow));
        accD += (d.x + d.y) + (d.z + d.w);
        const int srow = (n * C_DET + c) * (C_SEG * HW) + p4 * 4;
        if (mask & 1) {
            const f32x4 s = __builtin_nontemporal_load(
                reinterpret_cast<const f32x4*>(seg + srow + 0 * HW));
            a0 += s.x * d.x + s.y * d.y + s.z * d.z + s.w * d.w;
        }
        if (mask & 2) {
            const f32x4 s = __builtin_nontemporal_load(
                reinterpret_cast<const f32x4*>(seg + srow + 1 * HW));
            a1 += s.x * d.x + s.y * d.y + s.z * d.z + s.w * d.w;
        }
        if (mask & 4) {
            const f32x4 s = __builtin_nontemporal_load(
                reinterpret_cast<const f32x4*>(seg + srow + 2 * HW));
            a2 += s.x * d.x + s.y * d.y + s.z * d.z + s.w * d.w;
        }
        if (mask & 8) {
            const f32x4 s = __builtin_nontemporal_load(
                reinterpret_cast<const f32x4*>(seg + srow + 3 * HW));
            a3 += s.x * d.x + s.y * d.y + s.z * d.z + s.w * d.w;
        }
    };

    int t4 = bx * 256 + tid;
    // 2-way unroll: up to 6 outstanding 16B loads per thread
    for (; t4 + step < total4; t4 += 2 * step) {
        body(t4);
        body(t4 + step);
    }
    if (t4 < total4) body(t4);

    // ---- block-reduce 5 scalars: wave shuffle -> LDS -> partial store ----
    __shared__ float sred[5][4];
    const int lane = tid & 63;
    const int wv   = tid >> 6;
    float vals[5] = {accD, a0, a1, a2, a3};
    #pragma unroll
    for (int k = 0; k < 5; ++k) {
        float v = vals[k];
        #pragma unroll
        for (int off = 32; off > 0; off >>= 1) v += __shfl_down(v, off, 64);
        if (lane == 0) sred[k][wv] = v;
    }
    __syncthreads();
    if (tid < 5) {
        partial[(c * 5 + tid) * NBLK + bx] =
            sred[tid][0] + sred[tid][1] + sred[tid][2] + sred[tid][3];
    }
}

__global__ __launch_bounds__(256) void finalize_kernel(
    const float* __restrict__ det_class,  // [N_OBJ, C_DET]
    const int* __restrict__ edge_i,
    const int* __restrict__ edge_j,
    const int n_edges,
    const float* __restrict__ partial,
    float* __restrict__ out)
{
    const int tid  = threadIdx.x;
    const int lane = tid & 63;
    const int wv   = tid >> 6;

    // Prefetch det_class into registers to hide the cold miss behind stage 1.
    f32x4 ra[4], rb[4];
    #pragma unroll
    for (int r = 0; r < 4; ++r) {
        const int n = tid + 256 * r;
        ra[r] = *reinterpret_cast<const f32x4*>(det_class + n * C_DET);
        rb[r] = *reinterpret_cast<const f32x4*>(det_class + n * C_DET + 4);
    }

    // Stage 1: reduce 40 rows x 128 partials -> DA[c*5+k], no atomics.
    // Each wave owns 10 rows; per row: coalesced float2 load + shuffle tree.
    __shared__ float DA[C_DET * 5];
    #pragma unroll
    for (int q = 0; q < 10; ++q) {
        const int row = wv * 10 + q;
        const float2 v = *reinterpret_cast<const float2*>(
            partial + row * NBLK + lane * 2);
        float s = v.x + v.y;
        #pragma unroll
        for (int off = 32; off > 0; off >>= 1) s += __shfl_down(s, off, 64);
        if (lane == 0) DA[row] = s;
    }
    __syncthreads();

    // Stage 2: per-edge weights accumulated onto det class j.
    __shared__ float wsh[C_DET];
    if (tid < C_DET) wsh[tid] = 0.f;
    __syncthreads();
    if (tid < n_edges) {
        const int i = edge_i[tid];
        const int j = edge_j[tid];
        atomicAdd(&wsh[j], DA[j * 5 + 1 + i] / DA[j * 5]);
    }
    __syncthreads();

    float wl[C_DET];
    #pragma unroll
    for (int k = 0; k < C_DET; ++k) wl[k] = wsh[k];

    // Stage 3: probs = det_class @ w; loss = mean(-clip(log p, -100)).
    float acc = 0.f;
    #pragma unroll
    for (int r = 0; r < 4; ++r) {
        const float p = ra[r].x * wl[0] + ra[r].y * wl[1]
                      + ra[r].z * wl[2] + ra[r].w * wl[3]
                      + rb[r].x * wl[4] + rb[r].y * wl[5]
                      + rb[r].z * wl[6] + rb[r].w * wl[7];
        acc += -fmaxf(logf(p), -100.f);
    }

    __shared__ float fred[4];
    float v = acc;
    #pragma unroll
    for (int off = 32; off > 0; off >>= 1) v += __shfl_down(v, off, 64);
    if (lane == 0) fred[wv] = v;
    __syncthreads();
    if (tid == 0)
        out[0] = (fred[0] + fred[1] + fred[2] + fred[3]) * (1.0f / N_OBJ);
}

extern "C" void kernel_launch(void* const* d_in, const int* in_sizes, int n_in,
                              void* d_out, int out_size, void* d_ws, size_t ws_size,
                              hipStream_t stream) {
    const float* det_class = (const float*)d_in[0];   // [1024, 8]
    const float* det       = (const float*)d_in[1];   // [1024, 8, 28, 28]
    const float* seg       = (const float*)d_in[2];   // [1024, 8, 4, 28, 28]
    const int*   edge_i    = (const int*)d_in[3];
    const int*   edge_j    = (const int*)d_in[4];
    const int    n_edges   = in_sizes[3];
    float* out = (float*)d_out;
    float* partial = (float*)d_ws;   // 5120 floats

    overlap_kernel<<<dim3(NBLK, C_DET), 256, 0, stream>>>(
        det, seg, edge_i, edge_j, n_edges, partial);
    finalize_kernel<<<1, 256, 0, stream>>>(det_class, edge_i, edge_j, n_edges,
                                           partial, out);
}